// Round 1
// 225.612 us; speedup vs baseline: 1.1137x; 1.1137x over previous
//
#include <hip/hip_runtime.h>
#include <cstdint>
#include <cstddef>

// Problem constants: B=4,S=2048,D=1024,E=32,H=128,K=2
#define NTOK 8192
#define DIM  1024
#define NEXP 32
#define NH   128
#define TT   32               // tokens per FFN tile
#define NSLOT 32              // tile slots per expert (32*32 = 1024 = LCAP)
#define BK   128              // K-chunk for phase A
#define RT   32               // tokens per router block
#define LCAP 1024             // per-expert list capacity (mean 512, sigma~22)

typedef __attribute__((ext_vector_type(8))) short short8;
typedef __attribute__((ext_vector_type(4))) float float4_;

static __device__ __forceinline__ unsigned short f2bf(float f) {
  unsigned u = __float_as_uint(f);
  return (unsigned short)((u + 0x7fffu + ((u >> 16) & 1u)) >> 16);
}
static __device__ __forceinline__ float bf2f(unsigned short h) {
  return __uint_as_float(((unsigned)h) << 16);
}
// async global->LDS, 16 B/lane; LDS dest = uniform base + lane*16 (HW rule).
static __device__ __forceinline__ void gload_lds16(const unsigned short* g,
                                                   unsigned short* l) {
  __builtin_amdgcn_global_load_lds(
      (const __attribute__((address_space(1))) unsigned int*)(const void*)g,
      (__attribute__((address_space(3))) unsigned int*)(void*)l, 16, 0, 0);
}

// ---------------- Fused prep + router ---------------------------------------
// bid < 256: router over 32 tokens (fp32 logits for exact top-2) + x->bf16
// bid >= 256: weight transposes (original 32x32 tile scheme), lb in [0,8192)
__global__ __launch_bounds__(256) void prep_router_kernel(
    const float* __restrict__ x, const float* __restrict__ w_sel,
    const float* __restrict__ w_keys, const float* __restrict__ w_values,
    unsigned short* __restrict__ xbf, unsigned short* __restrict__ wk_t,
    unsigned short* __restrict__ wv_t,
    int* __restrict__ counts, unsigned* __restrict__ list)
{
  const int bid = blockIdx.x;
  const int tid = threadIdx.x;

  if (bid >= 256) {
    __shared__ float tile[32][33];
    const int lb = bid - 256;            // [0, 8192)
    const float* src; unsigned short* dst; int R, C, e, t;
    if (lb < 4096) { src = w_keys;   dst = wk_t; R = DIM; C = NH;  e = lb >> 7;          t = lb & 127; }
    else           { src = w_values; dst = wv_t; R = NH;  C = DIM; e = (lb - 4096) >> 7; t = (lb - 4096) & 127; }
    const int tpc = C >> 5;
    const int r0 = (t / tpc) * 32;
    const int c0 = (t % tpc) * 32;
    const float* s = src + (size_t)e * R * C;
    unsigned short* d = dst + (size_t)e * R * C;

    const int i = tid >> 3;              // 0..31
    const int j = (tid & 7) * 4;         // 0..28
    float4 v = *(const float4*)(s + (size_t)(r0 + i) * C + c0 + j);
    tile[i][j] = v.x; tile[i][j + 1] = v.y; tile[i][j + 2] = v.z; tile[i][j + 3] = v.w;
    __syncthreads();
    unsigned lo = (unsigned)f2bf(tile[j + 0][i]) | ((unsigned)f2bf(tile[j + 1][i]) << 16);
    unsigned hi = (unsigned)f2bf(tile[j + 2][i]) | ((unsigned)f2bf(tile[j + 3][i]) << 16);
    uint2 u; u.x = lo; u.y = hi;
    *(uint2*)(d + (size_t)(c0 + i) * R + r0 + j) = u;
    return;
  }

  // ---- router block (fp32 logits; also emits xbf from the same x loads) ----
  __shared__ __align__(16) float xs_t[64][36];   // [d][token]
  __shared__ float ws[NEXP][65];                 // [e][d]
  __shared__ float S[RT][33];                    // logits [token][e]

  const int tok0 = bid * RT;
  const int tr   = tid >> 3;
  const int d8   = (tid & 7) * 8;
  const int tg4  = (tid & 7) * 4;

  float acc[4] = {0.f, 0.f, 0.f, 0.f};

  for (int dc = 0; dc < DIM; dc += 64) {
    const float* xp = x + (size_t)(tok0 + tr) * DIM + dc + d8;
    float4 a0 = *(const float4*)(xp);
    float4 a1 = *(const float4*)(xp + 4);
    xs_t[d8 + 0][tr] = a0.x; xs_t[d8 + 1][tr] = a0.y;
    xs_t[d8 + 2][tr] = a0.z; xs_t[d8 + 3][tr] = a0.w;
    xs_t[d8 + 4][tr] = a1.x; xs_t[d8 + 5][tr] = a1.y;
    xs_t[d8 + 6][tr] = a1.z; xs_t[d8 + 7][tr] = a1.w;
    // fused x -> bf16 (replaces prep's second pass over x)
    uint4 u;
    u.x = (unsigned)f2bf(a0.x) | ((unsigned)f2bf(a0.y) << 16);
    u.y = (unsigned)f2bf(a0.z) | ((unsigned)f2bf(a0.w) << 16);
    u.z = (unsigned)f2bf(a1.x) | ((unsigned)f2bf(a1.y) << 16);
    u.w = (unsigned)f2bf(a1.z) | ((unsigned)f2bf(a1.w) << 16);
    *(uint4*)(xbf + (size_t)(tok0 + tr) * DIM + dc + d8) = u;

    const float* wp = w_sel + (size_t)tr * DIM + dc + d8;
    float4 b0 = *(const float4*)(wp);
    float4 b1 = *(const float4*)(wp + 4);
    ws[tr][d8 + 0] = b0.x; ws[tr][d8 + 1] = b0.y;
    ws[tr][d8 + 2] = b0.z; ws[tr][d8 + 3] = b0.w;
    ws[tr][d8 + 4] = b1.x; ws[tr][d8 + 5] = b1.y;
    ws[tr][d8 + 6] = b1.z; ws[tr][d8 + 7] = b1.w;
    __syncthreads();

    #pragma unroll 8
    for (int dd = 0; dd < 64; ++dd) {
      float w = ws[tr][dd];
      float4 xv = *(const float4*)&xs_t[dd][tg4];
      acc[0] += xv.x * w; acc[1] += xv.y * w;
      acc[2] += xv.z * w; acc[3] += xv.w * w;
    }
    __syncthreads();
  }

  #pragma unroll
  for (int j = 0; j < 4; ++j)
    S[tg4 + j][tr] = acc[j];
  __syncthreads();

  if (tid < RT) {
    const int t = tid;
    float m1 = -1e30f, m2 = -1e30f;
    int i1 = 0, i2 = 0;
    for (int ee = 0; ee < NEXP; ++ee) {
      float v = S[t][ee];
      if (v > m1)      { m2 = m1; i2 = i1; m1 = v; i1 = ee; }
      else if (v > m2) { m2 = v; i2 = ee; }
    }
    const int token = tok0 + t;
    float g1 = 1.f / (1.f + __expf(-m1));
    float g2 = 1.f / (1.f + __expf(-m2));
    unsigned e1 = ((unsigned)f2bf(g1) << 16) | ((unsigned)token << 1);
    unsigned e2 = ((unsigned)f2bf(g2) << 16) | ((unsigned)token << 1) | 1u;
    int p1 = atomicAdd(&counts[i1], 1);
    if (p1 < LCAP) list[i1 * LCAP + p1] = e1;
    int p2 = atomicAdd(&counts[i2], 1);
    if (p2 < LCAP) list[i2 * LCAP + p2] = e2;
  }
}

// ---------------- Expert FFN: TT=32 tiles, 2x working blocks, LDS-bounced
// stores. LDS ~26KB + launch_bounds(256,4) -> up to 4 blocks/CU resident.
__global__ __launch_bounds__(256, 4) void ffn_kernel(
    const unsigned short* __restrict__ xbf,
    const unsigned short* __restrict__ wk_t,   // bf16 [E][H][D]
    const unsigned short* __restrict__ wv_t,   // bf16 [E][D][H]
    float* __restrict__ out,                   // atomic mode
    unsigned short* __restrict__ cont,         // cont mode [2][NTOK][DIM] bf16
    const int* __restrict__ counts, const unsigned* __restrict__ list,
    int use_cont)
{
  const int bid = blockIdx.x;
  const int e   = bid & 31;                    // bid%8 == e%8 -> expert stays on one XCD
  const int cnt = min(counts[e], LCAP);
  const int t0  = (bid >> 5) * TT;
  if (t0 >= cnt) return;

  // xsf: A-fragments, frag (mt*4+kk)*512 + lane*8 (lane-contiguous for gload_lds)
  // st : store-bounce [32 rows][256 cols + pad], unioned with xsf (disjoint phases)
  __shared__ __align__(16) unsigned short uni[8448];   // max(2*4096, 32*264) shorts
  __shared__ unsigned short ss[TT][NH + 8];
  __shared__ int   toks[TT];
  __shared__ float gates[TT];
  unsigned short (*xsf)[4096] = (unsigned short (*)[4096])uni;
  unsigned short (*st)[264]   = (unsigned short (*)[264])uni;

  const int tid  = threadIdx.x;
  const int wave = tid >> 6;
  const int lane = tid & 63;
  const int quad = lane >> 4;
  const int l16  = lane & 15;

  const unsigned short* wkb = wk_t + (size_t)e * NH * DIM;
  const unsigned short* wvb = wv_t + (size_t)e * DIM * NH;
  const int n_tok = min(TT, cnt - t0);

  if (tid < TT) {
    int valid = tid < n_tok;
    unsigned en = valid ? list[e * LCAP + t0 + tid] : 0u;
    toks[tid]  = valid ? (int)(en & 0xffffu) : -1;
    gates[tid] = valid ? bf2f((unsigned short)(en >> 16)) : 0.f;
  }
  __syncthreads();

  // staging: waves {0,1} stage rows 0..15 (kk {0,1}/{2,3}), waves {2,3} rows 16..31
  const int smt  = wave >> 1;
  const int skk0 = (wave & 1) * 2;
  {
    int sl   = toks[smt * 16 + l16];
    int gtok = (sl < 0) ? 0 : (sl >> 1);
    const unsigned short* gsrc = xbf + (size_t)gtok * DIM + quad * 8;

    #pragma unroll
    for (int i2 = 0; i2 < 2; ++i2)
      gload_lds16(gsrc + (skk0 + i2) * 32, &xsf[0][(smt * 4 + skk0 + i2) * 512]);
    __syncthreads();

    // ---- Phase A: S = relu(X @ Wk) * gate  (M=32, N=128, K=1024)
    float4_ acc[2][2];
    #pragma unroll
    for (int mt = 0; mt < 2; ++mt)
      #pragma unroll
      for (int nt = 0; nt < 2; ++nt) acc[mt][nt] = (float4_){0.f, 0.f, 0.f, 0.f};

    for (int ci = 0; ci < 8; ++ci) {
      const int dc = ci * BK;
      if (ci < 7) {
        const int nb = (ci + 1) & 1;
        #pragma unroll
        for (int i2 = 0; i2 < 2; ++i2)
          gload_lds16(gsrc + dc + BK + (skk0 + i2) * 32,
                      &xsf[nb][(smt * 4 + skk0 + i2) * 512]);
      }
      short8 b[4][2];
      #pragma unroll
      for (int kk = 0; kk < 4; ++kk)
        #pragma unroll
        for (int nt = 0; nt < 2; ++nt)
          b[kk][nt] = *(const short8*)(wkb +
              (size_t)(wave * 32 + nt * 16 + l16) * DIM + dc + kk * 32 + quad * 8);

      const unsigned short* xb = &xsf[ci & 1][0];
      #pragma unroll
      for (int kk = 0; kk < 4; ++kk) {
        #pragma unroll
        for (int mt = 0; mt < 2; ++mt) {
          short8 a = *(const short8*)(xb + (mt * 4 + kk) * 512 + lane * 8);
          #pragma unroll
          for (int nt = 0; nt < 2; ++nt)
            acc[mt][nt] = __builtin_amdgcn_mfma_f32_16x16x32_bf16(a, b[kk][nt], acc[mt][nt], 0, 0, 0);
        }
      }
      __syncthreads();   // drains prefetch + protects buf reuse
    }

    // epilogue A: relu * gate -> bf16 scores
    #pragma unroll
    for (int mt = 0; mt < 2; ++mt)
      #pragma unroll
      for (int nt = 0; nt < 2; ++nt)
        #pragma unroll
        for (int r = 0; r < 4; ++r) {
          int row = mt * 16 + quad * 4 + r;
          float v = fmaxf(acc[mt][nt][r], 0.f) * gates[row];
          ss[row][wave * 32 + nt * 16 + l16] = f2bf(v);
        }
  }
  __syncthreads();       // xsf dead from here on -> st may alias it

  // ---- Phase B: O = S @ Wv  (M=32, N=1024, K=128)
  #pragma unroll 1
  for (int nc = 0; nc < 4; ++nc) {
    const int colbase = wave * 256 + nc * 64;
    float4_ o[2][4];
    #pragma unroll
    for (int mt = 0; mt < 2; ++mt)
      #pragma unroll
      for (int nt = 0; nt < 4; ++nt) o[mt][nt] = (float4_){0.f, 0.f, 0.f, 0.f};

    #pragma unroll
    for (int kk = 0; kk < 4; ++kk) {
      short8 bk[4];
      #pragma unroll
      for (int nt = 0; nt < 4; ++nt)
        bk[nt] = *(const short8*)(wvb +
            (size_t)(colbase + nt * 16 + l16) * NH + kk * 32 + quad * 8);
      short8 a0 = *(const short8*)&ss[l16][kk * 32 + quad * 8];
      short8 a1 = *(const short8*)&ss[16 + l16][kk * 32 + quad * 8];
      #pragma unroll
      for (int nt = 0; nt < 4; ++nt) {
        o[0][nt] = __builtin_amdgcn_mfma_f32_16x16x32_bf16(a0, bk[nt], o[0][nt], 0, 0, 0);
        o[1][nt] = __builtin_amdgcn_mfma_f32_16x16x32_bf16(a1, bk[nt], o[1][nt], 0, 0, 0);
      }
    }

    if (use_cont) {
      // bounce through LDS, then full 128B row-segment stores
      #pragma unroll
      for (int mt = 0; mt < 2; ++mt)
        #pragma unroll
        for (int nt = 0; nt < 4; ++nt)
          #pragma unroll
          for (int r = 0; r < 4; ++r)
            st[mt * 16 + quad * 4 + r][wave * 64 + nt * 16 + l16] = f2bf(o[mt][nt][r]);
      __syncthreads();
      #pragma unroll
      for (int q = 0; q < 4; ++q) {
        int idx = q * 256 + tid;
        int row = idx >> 5, seg = idx & 31;
        if (row < n_tok) {
          int sl2 = toks[row];
          size_t base = ((size_t)((sl2 & 1) * NTOK + (sl2 >> 1))) * DIM
                        + (seg >> 3) * 256 + nc * 64 + (seg & 7) * 8;
          *(short8*)&cont[base] = *(const short8*)&st[row][seg * 8];
        }
      }
      __syncthreads();   // st reused next nc
    } else {
      #pragma unroll
      for (int mt = 0; mt < 2; ++mt)
        #pragma unroll
        for (int r = 0; r < 4; ++r) {
          int row = mt * 16 + quad * 4 + r;
          if (row < n_tok) {
            size_t base = (size_t)(toks[row] >> 1) * DIM + colbase;
            #pragma unroll
            for (int nt = 0; nt < 4; ++nt)
              unsafeAtomicAdd(&out[base + nt * 16 + l16], o[mt][nt][r]);
          }
        }
    }
  }
}

// ---------------- Combine: out = cont[0] + cont[1] (bf16 -> f32) -----------
__global__ __launch_bounds__(256) void combine_kernel(
    const unsigned short* __restrict__ cont, float* __restrict__ out)
{
  size_t i = ((size_t)blockIdx.x * 256 + threadIdx.x) * 8;
  uint4 a = *(const uint4*)(cont + i);
  uint4 b = *(const uint4*)(cont + (size_t)NTOK * DIM + i);
  float4 r0, r1;
  r0.x = bf2f((unsigned short)(a.x & 0xffff)) + bf2f((unsigned short)(b.x & 0xffff));
  r0.y = bf2f((unsigned short)(a.x >> 16))    + bf2f((unsigned short)(b.x >> 16));
  r0.z = bf2f((unsigned short)(a.y & 0xffff)) + bf2f((unsigned short)(b.y & 0xffff));
  r0.w = bf2f((unsigned short)(a.y >> 16))    + bf2f((unsigned short)(b.y >> 16));
  r1.x = bf2f((unsigned short)(a.z & 0xffff)) + bf2f((unsigned short)(b.z & 0xffff));
  r1.y = bf2f((unsigned short)(a.z >> 16))    + bf2f((unsigned short)(b.z >> 16));
  r1.z = bf2f((unsigned short)(a.w & 0xffff)) + bf2f((unsigned short)(b.w & 0xffff));
  r1.w = bf2f((unsigned short)(a.w >> 16))    + bf2f((unsigned short)(b.w >> 16));
  *(float4*)(out + i) = r0;
  *(float4*)(out + i + 4) = r1;
}

extern "C" void kernel_launch(void* const* d_in, const int* in_sizes, int n_in,
                              void* d_out, int out_size, void* d_ws, size_t ws_size,
                              hipStream_t stream) {
  (void)in_sizes; (void)n_in;
  const float* x        = (const float*)d_in[0];
  const float* w_sel    = (const float*)d_in[1];
  const float* w_keys   = (const float*)d_in[2];
  const float* w_values = (const float*)d_in[3];
  float* out = (float*)d_out;

  // workspace layout
  char* ws = (char*)d_ws;
  size_t off = 0;
  int*            counts = (int*)(ws + off);            off += 4096;
  unsigned*       list   = (unsigned*)(ws + off);       off += (size_t)NEXP * LCAP * 4;      // 128 KB
  unsigned short* wk_t   = (unsigned short*)(ws + off); off += (size_t)NEXP * NH * DIM * 2;  // 8 MB
  unsigned short* wv_t   = (unsigned short*)(ws + off); off += (size_t)NEXP * NH * DIM * 2;  // 8 MB
  unsigned short* xbf    = (unsigned short*)(ws + off); off += (size_t)NTOK * DIM * 2;       // 16 MB
  unsigned short* cont   = (unsigned short*)(ws + off);
  size_t need_full = off + (size_t)2 * NTOK * DIM * 2;  // + 32 MB
  const int use_cont = (ws_size >= need_full) ? 1 : 0;

  hipMemsetAsync(counts, 0, NEXP * sizeof(int), stream);

  prep_router_kernel<<<256 + 8192, 256, 0, stream>>>(x, w_sel, w_keys, w_values,
                                                     xbf, wk_t, wv_t, counts, list);

  if (!use_cont)
    hipMemsetAsync(out, 0, (size_t)out_size * sizeof(float), stream);

  ffn_kernel<<<NEXP * NSLOT, 256, 0, stream>>>(xbf, wk_t, wv_t, out, cont,
                                               counts, list, use_cont);

  if (use_cont)
    combine_kernel<<<NTOK * DIM / (256 * 8), 256, 0, stream>>>(cont, out);
}